// Round 17
// baseline (177.268 us; speedup 1.0000x reference)
//
#include <hip/hip_runtime.h>
#include <hip/hip_bf16.h>

#define BB 64
#define SS 400
#define HH 512
#define EE 300
#define VV 50000
#define KD 812     // E+H (LSTM input width)
#define KG 1324    // 2H+E (gen_in width)
#define KC 1024    // 2H (out_cat width)
#define BV (BB*VV)

typedef __attribute__((ext_vector_type(8))) short bf16x8;
typedef __attribute__((ext_vector_type(4))) float f32x4;

// ---- workspace layout (float offsets) ----
#define WS_SCORE 0          // [B*S] raw scores
#define WS_ML    25600      // [512][2] chunk {m,l}
#define WS_MLB   26624      // [64][2] global {M,L}
#define WS_CTX   51200      // [64][512]
#define WS_HNEW  83968      // [64][512]
#define WS_G0    116736     // [2048][64] f32 gate partials x4
#define WS_G1    247808
#define WS_G2    378880
#define WS_G3    509952
#define WS_PGEN  641024     // [64]
#define WS_PART  641088     // [64][8][512] ctx partials
#define WS_ABF   903232     // ushort [64][1024] bf16 out_cat
#define WS_AD1   936000     // ushort [64][832]  bf16 [xe|ctx|0pad]
#define WS_AD2   962624     // ushort [64][512]  bf16 h_prev

__device__ __forceinline__ float sigm(float x){ return 1.f/(1.f+__expf(-x)); }
__device__ __forceinline__ float ftanh(float x){
  x = fminf(fmaxf(x,-15.f),15.f);
  float e = __expf(2.f*x);
  return (e-1.f)/(e+1.f);
}
__device__ __forceinline__ unsigned short f2bf(float f){
  unsigned int u = __builtin_bit_cast(unsigned int, f);
  u += 0x7fffu + ((u>>16)&1u);
  return (unsigned short)(u>>16);
}

// ---- compiler-scheduled pipelined MFMA segment (k_gates) ----
#define LDW(S, off) { w##S##0 = *(const float4*)(wr + (off)*32); \
                      w##S##1 = *(const float4*)(wr + (off)*32 + 4); }
#define LDA(S, off) { a##S##0 = *(const bf16x8*)(a0 + (off)*32); \
                      a##S##1 = *(const bf16x8*)(a1 + (off)*32); \
                      a##S##2 = *(const bf16x8*)(a2 + (off)*32); \
                      a##S##3 = *(const bf16x8*)(a3 + (off)*32); }
#define CONS(S) { union { bf16x8 v; unsigned int u[4]; } bb_; \
  float4 f0_ = w##S##0; float4 f1_ = w##S##1; \
  asm("v_cvt_pk_bf16_f32 %0, %1, %2" : "=v"(bb_.u[0]) : "v"(f0_.x), "v"(f0_.y)); \
  asm("v_cvt_pk_bf16_f32 %0, %1, %2" : "=v"(bb_.u[1]) : "v"(f0_.z), "v"(f0_.w)); \
  asm("v_cvt_pk_bf16_f32 %0, %1, %2" : "=v"(bb_.u[2]) : "v"(f1_.x), "v"(f1_.y)); \
  asm("v_cvt_pk_bf16_f32 %0, %1, %2" : "=v"(bb_.u[3]) : "v"(f1_.z), "v"(f1_.w)); \
  acc0 = __builtin_amdgcn_mfma_f32_16x16x32_bf16(a##S##0, bb_.v, acc0, 0,0,0); \
  acc1 = __builtin_amdgcn_mfma_f32_16x16x32_bf16(a##S##1, bb_.v, acc1, 0,0,0); \
  acc2 = __builtin_amdgcn_mfma_f32_16x16x32_bf16(a##S##2, bb_.v, acc2, 0,0,0); \
  acc3 = __builtin_amdgcn_mfma_f32_16x16x32_bf16(a##S##3, bb_.v, acc3, 0,0,0); }

template<int NSTEP>
__device__ __forceinline__ void mfma_seg2(const float* __restrict__ wr,
    const unsigned short* __restrict__ a0, const unsigned short* __restrict__ a1,
    const unsigned short* __restrict__ a2, const unsigned short* __restrict__ a3,
    f32x4& acc0, f32x4& acc1, f32x4& acc2, f32x4& acc3)
{
  static_assert(NSTEP % 2 == 0 && NSTEP >= 4, "");
  float4 wA0,wA1, wB0,wB1;
  bf16x8 aA0,aA1,aA2,aA3, aB0,aB1,aB2,aB3;
  LDW(A,0) LDA(A,0)
  LDW(B,1) LDA(B,1)
  #pragma unroll
  for (int ks=0; ks<NSTEP; ks+=2){
    CONS(A) if (ks+2 < NSTEP){ LDW(A,ks+2) LDA(A,ks+2) }
    CONS(B) if (ks+3 < NSTEP){ LDW(B,ks+3) LDA(B,ks+3) }
  }
}

// K1 (fused, + prep blocks): blocks [0,512): scores + online-softmax partials
// + ctx partial (enc read once). blocks [512,848): build ad1/ad2 bf16 buffers.
__global__ __launch_bounds__(256) void k_scorectx(const int* __restrict__ x,
    const float* __restrict__ emb, const float* __restrict__ enc,
    const float* __restrict__ h0, const float* __restrict__ Vw,
    const float* __restrict__ Vb, float* __restrict__ score,
    float* __restrict__ part, float* __restrict__ ml,
    unsigned short* __restrict__ ad1, unsigned short* __restrict__ ad2)
{
  __shared__ float wl[52];
  __shared__ float we[52];
  if (blockIdx.x >= 512){
    int n = (blockIdx.x - 512)*256 + threadIdx.x;
    if (n < BB*832){
      int b = n/832, k = n - b*832;
      if (k < EE) ad1[n] = f2bf(emb[(size_t)x[b]*EE + k]);
      else if (k >= 812) ad1[n] = 0;
    } else {
      int m = n - BB*832;
      ad2[m] = f2bf(h0[m]);
    }
    return;
  }
  int b = blockIdx.x >> 3, sp = blockIdx.x & 7;
  int t = threadIdx.x, w = t >> 6, lane = t & 63;
  int i0 = lane*8;
  const float4* hp = (const float4*)(h0 + b*HH + i0);
  const float4* vp = (const float4*)(Vw + i0);
  float4 hv0 = hp[0], hv1 = hp[1];
  float4 v0 = vp[0], v1 = vp[1];
  float vb = Vb[0];
  for (int r = w; r < 50; r += 4){
    int s = sp*50 + r;
    const float4* ep = (const float4*)(enc + ((size_t)b*SS + s)*HH + i0);
    float4 e0 = ep[0], e1 = ep[1];
    float sum = ftanh(e0.x+hv0.x)*v0.x + ftanh(e0.y+hv0.y)*v0.y
              + ftanh(e0.z+hv0.z)*v0.z + ftanh(e0.w+hv0.w)*v0.w
              + ftanh(e1.x+hv1.x)*v1.x + ftanh(e1.y+hv1.y)*v1.y
              + ftanh(e1.z+hv1.z)*v1.z + ftanh(e1.w+hv1.w)*v1.w;
    #pragma unroll
    for (int off=32; off; off>>=1) sum += __shfl_xor(sum, off);
    if (lane==0){ float sc = sum + vb; wl[r] = sc; score[b*SS + s] = sc; }
  }
  __syncthreads();
  float mx = -1e30f;
  for (int s=0; s<50; ++s) mx = fmaxf(mx, wl[s]);
  if (t < 50) we[t] = __expf(wl[t] - mx);
  __syncthreads();
  float l = 0.f;
  for (int s=0; s<50; ++s) l += we[s];
  float a0 = 0.f, a1 = 0.f;
  const float* ebase = enc + ((size_t)b*SS + sp*50)*HH + 2*t;
  #pragma unroll 5
  for (int s=0; s<50; ++s){
    float wg = we[s];
    float2 e = *(const float2*)(ebase + s*HH);
    a0 += wg * e.x;
    a1 += wg * e.y;
  }
  *(float2*)(part + (size_t)(b*8+sp)*HH + 2*t) = make_float2(a0, a1);
  if (t == 0){ ml[(b*8+sp)*2] = mx; ml[(b*8+sp)*2+1] = l; }
}

// K2: combine partials -> ctx, ad1, {M,L}
__global__ __launch_bounds__(256) void k_ctx_reduce(const float* __restrict__ part,
    const float* __restrict__ ml, float* __restrict__ ctx,
    unsigned short* __restrict__ ad1, float* __restrict__ mlb)
{
  int b = blockIdx.x, t = threadIdx.x;
  float M = -1e30f;
  #pragma unroll
  for (int c=0; c<8; ++c) M = fmaxf(M, ml[(b*8+c)*2]);
  float L = 0.f, sc[8];
  #pragma unroll
  for (int c=0; c<8; ++c){
    sc[c] = __expf(ml[(b*8+c)*2] - M);
    L += ml[(b*8+c)*2+1] * sc[c];
  }
  float inv = 1.f / L;
  float a0=0.f, a1=0.f;
  #pragma unroll
  for (int c=0; c<8; ++c){
    float2 e = *(const float2*)(part + (size_t)(b*8+c)*HH + 2*t);
    a0 += sc[c]*e.x; a1 += sc[c]*e.y;
  }
  a0 *= inv; a1 *= inv;
  *(float2*)(ctx + b*HH + 2*t) = make_float2(a0, a1);
  ad1[b*832 + EE + 2*t]     = f2bf(a0);
  ad1[b*832 + EE + 2*t + 1] = f2bf(a1);
  if (t == 0){ mlb[b*2] = M; mlb[b*2+1] = L; }
}

// K4: gates via MFMA (unchanged)
__global__ __launch_bounds__(128, 4) void k_gates(const float* __restrict__ Wih,
    const float* __restrict__ Whh, const unsigned short* __restrict__ ad1,
    const unsigned short* __restrict__ ad2,
    float* __restrict__ g0, float* __restrict__ g1,
    float* __restrict__ g2, float* __restrict__ g3)
{
  int wt = blockIdx.x*2 + (threadIdx.x >> 6);
  int lane = threadIdx.x & 63;
  int col = lane & 15, kg = lane >> 4;
  int jt = wt >> 2, part = wt & 3;
  int j = jt*16 + col;
  f32x4 acc0={0.f,0.f,0.f,0.f}, acc1=acc0, acc2=acc0, acc3=acc0;
  float* g;
  if (part < 2){
    int k0 = part ? 384 : 0;
    const float* wr = Wih + (size_t)j*KD + k0 + kg*8;
    const unsigned short* a = ad1 + col*832 + k0 + kg*8;
    if (part) mfma_seg2<14>(wr, a, a+16*832, a+32*832, a+48*832, acc0,acc1,acc2,acc3);
    else      mfma_seg2<12>(wr, a, a+16*832, a+32*832, a+48*832, acc0,acc1,acc2,acc3);
    g = part ? g1 : g0;
  } else {
    int k0 = (part==3) ? 256 : 0;
    const float* wr = Whh + (size_t)j*HH + k0 + kg*8;
    const unsigned short* a = ad2 + col*512 + k0 + kg*8;
    mfma_seg2<8>(wr, a, a+16*512, a+32*512, a+48*512, acc0,acc1,acc2,acc3);
    g = (part==3) ? g3 : g2;
  }
  #pragma unroll
  for (int i=0;i<4;i++){
    g[(size_t)j*BB + 0*16 + kg*4 + i] = acc0[i];
    g[(size_t)j*BB + 1*16 + kg*4 + i] = acc1[i];
    g[(size_t)j*BB + 2*16 + kg*4 + i] = acc2[i];
    g[(size_t)j*BB + 3*16 + kg*4 + i] = acc3[i];
  }
}

// K5: LSTM cell elementwise (unchanged)
__global__ __launch_bounds__(256) void k_lstm(const float* __restrict__ c0,
    const float* __restrict__ bih, const float* __restrict__ bhh,
    const float* __restrict__ g0, const float* __restrict__ g1,
    const float* __restrict__ g2, const float* __restrict__ g3,
    const float* __restrict__ ctx, float* __restrict__ hnew,
    unsigned short* __restrict__ abf, float* __restrict__ out)
{
  int n = blockIdx.x*256 + threadIdx.x;
  int b = n & 63, h = n >> 6;
  #define GSUM(off) (g0[(off)*BB+b] + g1[(off)*BB+b] + g2[(off)*BB+b] + g3[(off)*BB+b] + bih[off] + bhh[off])
  float gi = GSUM(h);
  float gf = GSUM(HH+h);
  float gg = GSUM(2*HH+h);
  float go = GSUM(3*HH+h);
  #undef GSUM
  float cn = sigm(gf)*c0[b*HH+h] + sigm(gi)*ftanh(gg);
  float hn = sigm(go)*ftanh(cn);
  out[BV + b*HH + h]          = hn;
  out[BV + BB*HH + b*HH + h]  = cn;
  hnew[b*HH + h] = hn;
  abf[b*KC + h]      = f2bf(hn);
  abf[b*KC + HH + h] = f2bf(ctx[b*HH + h]);
}

// K6: p_gen[b] (unchanged)
__global__ __launch_bounds__(256) void k_pgen(const float* __restrict__ genw,
    const float* __restrict__ genb, const float* __restrict__ ctx,
    const float* __restrict__ hnew, const int* __restrict__ x,
    const float* __restrict__ emb, float* __restrict__ pgen)
{
  __shared__ float red[256];
  int b = blockIdx.x, t = threadIdx.x;
  float p = 0.f;
  for (int k=t; k<KG; k+=256){
    float g = genw[k];
    float v = (k < HH) ? ctx[b*HH + k]
            : (k < 2*HH) ? hnew[b*HH + k - HH]
            : emb[(size_t)x[b]*EE + (k - 2*HH)];
    p += g*v;
  }
  red[t] = p; __syncthreads();
  for (int o=128; o; o>>=1){ if (t<o) red[t] += red[t+o]; __syncthreads(); }
  if (t==0) pgen[b] = sigm(red[0] + genb[0]);
}

// K7 v16-DIAG x2: identical pipeline to R16 (all-asm counted-vmcnt), whole
// body repeated 2x (idempotent stores, memory clobber between reps) so the
// dispatch exceeds the 115us fills and lands in the rocprof top-5 with full
// counters. FIFO-safe across reps: rep-2's first WAITV(9) drains rep-1's 4
// epilogue stores + pa/pg/A exactly (4+53-9=48). REVERT TO x1 NEXT ROUND.
#define PADH 2064   // padded LDS row stride (2048 + 16)
#define GLDX4(dst, ptr) asm volatile("global_load_dwordx4 %0, %1, off" : "=v"(dst) : "v"(ptr));
#define GLD1(dst, ptr)  asm volatile("global_load_dword %0, %1, off"   : "=v"(dst) : "v"(ptr));
#define WAITV(N) { asm volatile("s_waitcnt vmcnt(" #N ")" ::: "memory"); \
                   __builtin_amdgcn_sched_barrier(0); }
#define BARR() { asm volatile("s_waitcnt lgkmcnt(0)" ::: "memory"); \
                 __builtin_amdgcn_sched_barrier(0); \
                 __builtin_amdgcn_s_barrier(); \
                 __builtin_amdgcn_sched_barrier(0); }

__global__ __launch_bounds__(256, 2) void k_gemm(const float* __restrict__ out_w,
    const float* __restrict__ out_b, const unsigned short* __restrict__ abf,
    const float* __restrict__ pgen, float* __restrict__ out)
{
  __shared__ __align__(16) char wlds[2][16*PADH];   // 2 x 33 KB
  int t = threadIdx.x, w = t >> 6, lane = t & 63;
  int col = lane & 15, kg = lane >> 4;
  int bid = blockIdx.x;
  int ts = (bid * 3125) >> 9;
  int te = ((bid + 1) * 3125) >> 9;

  int gtb = ((t >> 7) << 12) + ((t & 127) << 4);   // global base in 32KB half
  int ltb = (t >> 7) * PADH + ((t & 127) << 4);    // LDS base (rows step by 2)

  #define WLOAD(S, tile_, kh_) { \
    const char* gp_ = (const char*)out_w + (size_t)(tile_)*65536 + (kh_)*2048 + gtb; \
    GLDX4(s##S##_0, (gp_)) \
    GLDX4(s##S##_1, (gp_ + 8192)) \
    GLDX4(s##S##_2, (gp_ + 16384)) \
    GLDX4(s##S##_3, (gp_ + 24576)) \
    GLDX4(s##S##_4, (gp_ + 32768)) \
    GLDX4(s##S##_5, (gp_ + 40960)) \
    GLDX4(s##S##_6, (gp_ + 49152)) \
    GLDX4(s##S##_7, (gp_ + 57344)) }

  #define WSTORE(S, buf_) { \
    char* lp_ = &wlds[buf_][0] + ltb; \
    *(f32x4*)(lp_)            = s##S##_0; \
    *(f32x4*)(lp_ + 2*PADH)   = s##S##_1; \
    *(f32x4*)(lp_ + 4*PADH)   = s##S##_2; \
    *(f32x4*)(lp_ + 6*PADH)   = s##S##_3; \
    *(f32x4*)(lp_ + 8*PADH)   = s##S##_4; \
    *(f32x4*)(lp_ + 10*PADH)  = s##S##_5; \
    *(f32x4*)(lp_ + 12*PADH)  = s##S##_6; \
    *(f32x4*)(lp_ + 14*PADH)  = s##S##_7; }

  #define COMPH(buf_, PA_) { \
    const char* rb_ = &wlds[buf_][0] + col*PADH + kg*32; \
    _Pragma("unroll") \
    for (int ks=0; ks<16; ++ks){ \
      float4 f0 = *(const float4*)(rb_ + ks*128); \
      float4 f1 = *(const float4*)(rb_ + ks*128 + 16); \
      union { bf16x8 v; unsigned int u[4]; } bb; \
      asm("v_cvt_pk_bf16_f32 %0, %1, %2" : "=v"(bb.u[0]) : "v"(f0.x), "v"(f0.y)); \
      asm("v_cvt_pk_bf16_f32 %0, %1, %2" : "=v"(bb.u[1]) : "v"(f0.z), "v"(f0.w)); \
      asm("v_cvt_pk_bf16_f32 %0, %1, %2" : "=v"(bb.u[2]) : "v"(f1.x), "v"(f1.y)); \
      asm("v_cvt_pk_bf16_f32 %0, %1, %2" : "=v"(bb.u[3]) : "v"(f1.z), "v"(f1.w)); \
      acc = __builtin_amdgcn_mfma_f32_16x16x32_bf16(PA_[ks], bb.v, acc, 0,0,0); \
    } }

  #pragma unroll 1
  for (int rep = 0; rep < 2; ++rep){
    // ---- prologue (per rep): every load is asm
    bf16x8 pa0[16], pa1[16];
    const unsigned short* ap = abf + (size_t)(w*16 + col)*KC + kg*8;
    #pragma unroll
    for (int k=0; k<16; ++k){ GLDX4(pa0[k], (ap + k*32)) }
    #pragma unroll
    for (int k=0; k<16; ++k){ GLDX4(pa1[k], (ap + 512 + k*32)) }
    float pg0, pg1, pg2, pg3;
    {
      const float* pb = pgen + w*16 + kg*4;
      GLD1(pg0, (pb)) GLD1(pg1, (pb+1)) GLD1(pg2, (pb+2)) GLD1(pg3, (pb+3))
    }

    f32x4 sA_0,sA_1,sA_2,sA_3,sA_4,sA_5,sA_6,sA_7;
    f32x4 sB_0,sB_1,sB_2,sB_3,sB_4,sB_5,sB_6,sB_7;
    float obA, obB;

    WLOAD(A, ts, 0)
    GLD1(obA, (out_b + ts*16 + col))
    WLOAD(B, ts, 1)

    f32x4 acc = {0.f,0.f,0.f,0.f};
    #pragma unroll 1
    for (int tile = ts; tile < te; ++tile){
      // ---- kh = 0
      WAITV(9)
      WSTORE(A, 0)
      if (tile + 1 < te){
        WLOAD(A, tile+1, 0)
        GLD1(obB, (out_b + (tile+1)*16 + col))
      }
      BARR()
      COMPH(0, pa0)
      // ---- kh = 1
      if (tile + 1 < te){ WAITV(9) } else { WAITV(0) }
      WSTORE(B, 1)
      if (tile + 1 < te) WLOAD(B, tile+1, 1)
      BARR()
      COMPH(1, pa1)
      // ---- epilogue (wave-local)
      {
        int v = tile*16 + col;
        int b0 = w*16 + kg*4;
        out[(size_t)(b0+0)*VV + v] = pg0*(acc[0] + obA);
        out[(size_t)(b0+1)*VV + v] = pg1*(acc[1] + obA);
        out[(size_t)(b0+2)*VV + v] = pg2*(acc[2] + obA);
        out[(size_t)(b0+3)*VV + v] = pg3*(acc[3] + obA);
      }
      acc = (f32x4){0.f,0.f,0.f,0.f};
      obA = obB;
    }
    asm volatile("" ::: "memory");
    __builtin_amdgcn_s_barrier();
  }
  #undef WLOAD
  #undef WSTORE
  #undef COMPH
}

// K8: pointer scatter, last-duplicate-wins; weights from score+{M,L}.
__global__ __launch_bounds__(256) void k_scatter(const int* __restrict__ text,
    const float* __restrict__ score, const float* __restrict__ mlb,
    const float* __restrict__ pgen, float* __restrict__ out)
{
  __shared__ int ts[SS];
  int b = blockIdx.x, t = threadIdx.x;
  ts[t] = text[b*SS + t];
  if (t + 256 < SS) ts[t+256] = text[b*SS + t + 256];
  __syncthreads();
  float pp = 1.f - pgen[b];
  float M = mlb[b*2], invL = 1.f / mlb[b*2+1];
  #pragma unroll
  for (int rep=0; rep<2; ++rep){
    int s = t + rep*256;
    if (s < SS){
      int v = ts[s];
      bool dup = false;
      #pragma unroll 4
      for (int s2=s+1; s2<SS; ++s2) dup = dup || (ts[s2]==v);
      if (!dup){
        float wgt = __expf(score[b*SS + s] - M) * invL;
        out[(size_t)b*VV + v] += pp * wgt;
      }
    }
  }
}

extern "C" void kernel_launch(void* const* d_in, const int* in_sizes, int n_in,
                              void* d_out, int out_size, void* d_ws, size_t ws_size,
                              hipStream_t stream)
{
  const int*   x    = (const int*)  d_in[0];
  const float* enc  = (const float*)d_in[1];
  const float* h0   = (const float*)d_in[2];
  const float* c0   = (const float*)d_in[3];
  const int*   text = (const int*)  d_in[4];
  const float* emb  = (const float*)d_in[6];
  const float* Vw   = (const float*)d_in[7];
  const float* Vb   = (const float*)d_in[8];
  const float* genw = (const float*)d_in[9];
  const float* genb = (const float*)d_in[10];
  const float* outw = (const float*)d_in[11];
  const float* outb = (const float*)d_in[12];
  const float* Wih  = (const float*)d_in[13];
  const float* Whh  = (const float*)d_in[14];
  const float* bih  = (const float*)d_in[15];
  const float* bhh  = (const float*)d_in[16];
  float* out = (float*)d_out;

  float* ws     = (float*)d_ws;
  float* score  = ws + WS_SCORE;
  float* ml     = ws + WS_ML;
  float* mlb    = ws + WS_MLB;
  float* ctx    = ws + WS_CTX;
  float* hnew   = ws + WS_HNEW;
  float* g0     = ws + WS_G0;
  float* g1     = ws + WS_G1;
  float* g2     = ws + WS_G2;
  float* g3     = ws + WS_G3;
  float* pgen   = ws + WS_PGEN;
  float* part   = ws + WS_PART;
  unsigned short* abf = (unsigned short*)(ws + WS_ABF);
  unsigned short* ad1 = (unsigned short*)(ws + WS_AD1);
  unsigned short* ad2 = (unsigned short*)(ws + WS_AD2);

  k_scorectx<<<848, 256, 0, stream>>>(x, emb, enc, h0, Vw, Vb, score, part, ml, ad1, ad2);
  k_ctx_reduce<<<64, 256, 0, stream>>>(part, ml, ctx, ad1, mlb);
  k_gates<<<256, 128, 0, stream>>>(Wih, Whh, ad1, ad2, g0, g1, g2, g3);
  k_lstm<<<128, 256, 0, stream>>>(c0, bih, bhh, g0, g1, g2, g3, ctx, hnew, abf, out);
  k_pgen<<<64, 256, 0, stream>>>(genw, genb, ctx, hnew, x, emb, pgen);
  k_gemm<<<512, 256, 0, stream>>>(outw, outb, abf, pgen, out);
  k_scatter<<<64, 256, 0, stream>>>(text, score, mlb, pgen, out);
}

// Round 18
// 116.271 us; speedup vs baseline: 1.5246x; 1.5246x over previous
//
#include <hip/hip_runtime.h>
#include <hip/hip_bf16.h>

#define BB 64
#define SS 400
#define HH 512
#define EE 300
#define VV 50000
#define KD 812     // E+H (LSTM input width)
#define KG 1324    // 2H+E (gen_in width)
#define KC 1024    // 2H (out_cat width)
#define BV (BB*VV)

typedef __attribute__((ext_vector_type(8))) short bf16x8;
typedef __attribute__((ext_vector_type(4))) float f32x4;

// ---- workspace layout (float offsets) ----
#define WS_SCORE 0          // [B*S] raw scores
#define WS_ML    25600      // [512][2] chunk {m,l}
#define WS_MLB   26624      // [64][2] global {M,L}
#define WS_CTX   51200      // [64][512]
#define WS_HNEW  83968      // [64][512]
#define WS_G0    116736     // [2048][64] f32 gate partials x4
#define WS_G1    247808
#define WS_G2    378880
#define WS_G3    509952
#define WS_PGEN  641024     // [64]
#define WS_PART  641088     // [64][8][512] ctx partials
#define WS_ABF   903232     // ushort [64][1024] bf16 out_cat
#define WS_AD1   936000     // ushort [64][832]  bf16 [xe|ctx|0pad]
#define WS_AD2   962624     // ushort [64][512]  bf16 h_prev

__device__ __forceinline__ float sigm(float x){ return 1.f/(1.f+__expf(-x)); }
__device__ __forceinline__ float ftanh(float x){
  x = fminf(fmaxf(x,-15.f),15.f);
  float e = __expf(2.f*x);
  return (e-1.f)/(e+1.f);
}
__device__ __forceinline__ unsigned short f2bf(float f){
  unsigned int u = __builtin_bit_cast(unsigned int, f);
  u += 0x7fffu + ((u>>16)&1u);
  return (unsigned short)(u>>16);
}

// ---- compiler-scheduled pipelined MFMA segment (k_gates) ----
#define LDW(S, off) { w##S##0 = *(const float4*)(wr + (off)*32); \
                      w##S##1 = *(const float4*)(wr + (off)*32 + 4); }
#define LDA(S, off) { a##S##0 = *(const bf16x8*)(a0 + (off)*32); \
                      a##S##1 = *(const bf16x8*)(a1 + (off)*32); \
                      a##S##2 = *(const bf16x8*)(a2 + (off)*32); \
                      a##S##3 = *(const bf16x8*)(a3 + (off)*32); }
#define CONS(S) { union { bf16x8 v; unsigned int u[4]; } bb_; \
  float4 f0_ = w##S##0; float4 f1_ = w##S##1; \
  asm("v_cvt_pk_bf16_f32 %0, %1, %2" : "=v"(bb_.u[0]) : "v"(f0_.x), "v"(f0_.y)); \
  asm("v_cvt_pk_bf16_f32 %0, %1, %2" : "=v"(bb_.u[1]) : "v"(f0_.z), "v"(f0_.w)); \
  asm("v_cvt_pk_bf16_f32 %0, %1, %2" : "=v"(bb_.u[2]) : "v"(f1_.x), "v"(f1_.y)); \
  asm("v_cvt_pk_bf16_f32 %0, %1, %2" : "=v"(bb_.u[3]) : "v"(f1_.z), "v"(f1_.w)); \
  acc0 = __builtin_amdgcn_mfma_f32_16x16x32_bf16(a##S##0, bb_.v, acc0, 0,0,0); \
  acc1 = __builtin_amdgcn_mfma_f32_16x16x32_bf16(a##S##1, bb_.v, acc1, 0,0,0); \
  acc2 = __builtin_amdgcn_mfma_f32_16x16x32_bf16(a##S##2, bb_.v, acc2, 0,0,0); \
  acc3 = __builtin_amdgcn_mfma_f32_16x16x32_bf16(a##S##3, bb_.v, acc3, 0,0,0); }

template<int NSTEP>
__device__ __forceinline__ void mfma_seg2(const float* __restrict__ wr,
    const unsigned short* __restrict__ a0, const unsigned short* __restrict__ a1,
    const unsigned short* __restrict__ a2, const unsigned short* __restrict__ a3,
    f32x4& acc0, f32x4& acc1, f32x4& acc2, f32x4& acc3)
{
  static_assert(NSTEP % 2 == 0 && NSTEP >= 4, "");
  float4 wA0,wA1, wB0,wB1;
  bf16x8 aA0,aA1,aA2,aA3, aB0,aB1,aB2,aB3;
  LDW(A,0) LDA(A,0)
  LDW(B,1) LDA(B,1)
  #pragma unroll
  for (int ks=0; ks<NSTEP; ks+=2){
    CONS(A) if (ks+2 < NSTEP){ LDW(A,ks+2) LDA(A,ks+2) }
    CONS(B) if (ks+3 < NSTEP){ LDW(B,ks+3) LDA(B,ks+3) }
  }
}

// K1 (fused): blocks [0,512): single-pass online-softmax attention — each
// wave computes scores for its rows AND accumulates exp*enc immediately
// (enc row already in registers), with running-max rescale; 4 wave-partials
// combined via LDS. blocks [512,848): build ad1/ad2 bf16 buffers.
__global__ __launch_bounds__(256) void k_scorectx(const int* __restrict__ x,
    const float* __restrict__ emb, const float* __restrict__ enc,
    const float* __restrict__ h0, const float* __restrict__ Vw,
    const float* __restrict__ Vb, float* __restrict__ score,
    float* __restrict__ part, float* __restrict__ ml,
    unsigned short* __restrict__ ad1, unsigned short* __restrict__ ad2)
{
  __shared__ float cls[4][512];
  __shared__ float cml[4][2];
  if (blockIdx.x >= 512){
    int n = (blockIdx.x - 512)*256 + threadIdx.x;
    if (n < BB*832){
      int b = n/832, k = n - b*832;
      if (k < EE) ad1[n] = f2bf(emb[(size_t)x[b]*EE + k]);
      else if (k >= 812) ad1[n] = 0;
    } else {
      int m = n - BB*832;
      ad2[m] = f2bf(h0[m]);
    }
    return;
  }
  int b = blockIdx.x >> 3, sp = blockIdx.x & 7;
  int t = threadIdx.x, w = t >> 6, lane = t & 63;
  int i0 = lane*8;
  const float4* hp = (const float4*)(h0 + b*HH + i0);
  const float4* vp = (const float4*)(Vw + i0);
  float4 hv0 = hp[0], hv1 = hp[1];
  float4 v0 = vp[0], v1 = vp[1];
  float vb = Vb[0];

  float m = -1e30f, l = 0.f;
  float4 c0 = {0.f,0.f,0.f,0.f}, c1 = {0.f,0.f,0.f,0.f};
  for (int r = w; r < 50; r += 4){
    int s = sp*50 + r;
    const float4* ep = (const float4*)(enc + ((size_t)b*SS + s)*HH + i0);
    float4 e0 = ep[0], e1 = ep[1];
    float sum = ftanh(e0.x+hv0.x)*v0.x + ftanh(e0.y+hv0.y)*v0.y
              + ftanh(e0.z+hv0.z)*v0.z + ftanh(e0.w+hv0.w)*v0.w
              + ftanh(e1.x+hv1.x)*v1.x + ftanh(e1.y+hv1.y)*v1.y
              + ftanh(e1.z+hv1.z)*v1.z + ftanh(e1.w+hv1.w)*v1.w;
    #pragma unroll
    for (int off=32; off; off>>=1) sum += __shfl_xor(sum, off);
    float sc = sum + vb;
    if (lane==0) score[b*SS + s] = sc;
    float mn = fmaxf(m, sc);
    float sl = __expf(m - mn);      // m=-1e30 first iter -> 0
    float p  = __expf(sc - mn);
    l = l*sl + p;
    c0.x = c0.x*sl + p*e0.x;  c0.y = c0.y*sl + p*e0.y;
    c0.z = c0.z*sl + p*e0.z;  c0.w = c0.w*sl + p*e0.w;
    c1.x = c1.x*sl + p*e1.x;  c1.y = c1.y*sl + p*e1.y;
    c1.z = c1.z*sl + p*e1.z;  c1.w = c1.w*sl + p*e1.w;
    m = mn;
  }
  *(float4*)&cls[w][i0]     = c0;
  *(float4*)&cls[w][i0 + 4] = c1;
  if (lane == 0){ cml[w][0] = m; cml[w][1] = l; }
  __syncthreads();

  // block combine: thread t handles k = 2t, 2t+1
  float M = fmaxf(fmaxf(cml[0][0], cml[1][0]), fmaxf(cml[2][0], cml[3][0]));
  float sw0 = __expf(cml[0][0]-M), sw1 = __expf(cml[1][0]-M);
  float sw2 = __expf(cml[2][0]-M), sw3 = __expf(cml[3][0]-M);
  float L = cml[0][1]*sw0 + cml[1][1]*sw1 + cml[2][1]*sw2 + cml[3][1]*sw3;
  float a0 = sw0*cls[0][2*t] + sw1*cls[1][2*t] + sw2*cls[2][2*t] + sw3*cls[3][2*t];
  float a1 = sw0*cls[0][2*t+1] + sw1*cls[1][2*t+1] + sw2*cls[2][2*t+1] + sw3*cls[3][2*t+1];
  *(float2*)(part + (size_t)(b*8+sp)*HH + 2*t) = make_float2(a0, a1);
  if (t == 0){ ml[(b*8+sp)*2] = M; ml[(b*8+sp)*2+1] = L; }
}

// K2: combine partials -> ctx, ad1, {M,L}
__global__ __launch_bounds__(256) void k_ctx_reduce(const float* __restrict__ part,
    const float* __restrict__ ml, float* __restrict__ ctx,
    unsigned short* __restrict__ ad1, float* __restrict__ mlb)
{
  int b = blockIdx.x, t = threadIdx.x;
  float M = -1e30f;
  #pragma unroll
  for (int c=0; c<8; ++c) M = fmaxf(M, ml[(b*8+c)*2]);
  float L = 0.f, sc[8];
  #pragma unroll
  for (int c=0; c<8; ++c){
    sc[c] = __expf(ml[(b*8+c)*2] - M);
    L += ml[(b*8+c)*2+1] * sc[c];
  }
  float inv = 1.f / L;
  float a0=0.f, a1=0.f;
  #pragma unroll
  for (int c=0; c<8; ++c){
    float2 e = *(const float2*)(part + (size_t)(b*8+c)*HH + 2*t);
    a0 += sc[c]*e.x; a1 += sc[c]*e.y;
  }
  a0 *= inv; a1 *= inv;
  *(float2*)(ctx + b*HH + 2*t) = make_float2(a0, a1);
  ad1[b*832 + EE + 2*t]     = f2bf(a0);
  ad1[b*832 + EE + 2*t + 1] = f2bf(a1);
  if (t == 0){ mlb[b*2] = M; mlb[b*2+1] = L; }
}

// K4: gates via MFMA (unchanged)
__global__ __launch_bounds__(128, 4) void k_gates(const float* __restrict__ Wih,
    const float* __restrict__ Whh, const unsigned short* __restrict__ ad1,
    const unsigned short* __restrict__ ad2,
    float* __restrict__ g0, float* __restrict__ g1,
    float* __restrict__ g2, float* __restrict__ g3)
{
  int wt = blockIdx.x*2 + (threadIdx.x >> 6);
  int lane = threadIdx.x & 63;
  int col = lane & 15, kg = lane >> 4;
  int jt = wt >> 2, part = wt & 3;
  int j = jt*16 + col;
  f32x4 acc0={0.f,0.f,0.f,0.f}, acc1=acc0, acc2=acc0, acc3=acc0;
  float* g;
  if (part < 2){
    int k0 = part ? 384 : 0;
    const float* wr = Wih + (size_t)j*KD + k0 + kg*8;
    const unsigned short* a = ad1 + col*832 + k0 + kg*8;
    if (part) mfma_seg2<14>(wr, a, a+16*832, a+32*832, a+48*832, acc0,acc1,acc2,acc3);
    else      mfma_seg2<12>(wr, a, a+16*832, a+32*832, a+48*832, acc0,acc1,acc2,acc3);
    g = part ? g1 : g0;
  } else {
    int k0 = (part==3) ? 256 : 0;
    const float* wr = Whh + (size_t)j*HH + k0 + kg*8;
    const unsigned short* a = ad2 + col*512 + k0 + kg*8;
    mfma_seg2<8>(wr, a, a+16*512, a+32*512, a+48*512, acc0,acc1,acc2,acc3);
    g = (part==3) ? g3 : g2;
  }
  #pragma unroll
  for (int i=0;i<4;i++){
    g[(size_t)j*BB + 0*16 + kg*4 + i] = acc0[i];
    g[(size_t)j*BB + 1*16 + kg*4 + i] = acc1[i];
    g[(size_t)j*BB + 2*16 + kg*4 + i] = acc2[i];
    g[(size_t)j*BB + 3*16 + kg*4 + i] = acc3[i];
  }
}

// K5: LSTM cell elementwise (unchanged)
__global__ __launch_bounds__(256) void k_lstm(const float* __restrict__ c0,
    const float* __restrict__ bih, const float* __restrict__ bhh,
    const float* __restrict__ g0, const float* __restrict__ g1,
    const float* __restrict__ g2, const float* __restrict__ g3,
    const float* __restrict__ ctx, float* __restrict__ hnew,
    unsigned short* __restrict__ abf, float* __restrict__ out)
{
  int n = blockIdx.x*256 + threadIdx.x;
  int b = n & 63, h = n >> 6;
  #define GSUM(off) (g0[(off)*BB+b] + g1[(off)*BB+b] + g2[(off)*BB+b] + g3[(off)*BB+b] + bih[off] + bhh[off])
  float gi = GSUM(h);
  float gf = GSUM(HH+h);
  float gg = GSUM(2*HH+h);
  float go = GSUM(3*HH+h);
  #undef GSUM
  float cn = sigm(gf)*c0[b*HH+h] + sigm(gi)*ftanh(gg);
  float hn = sigm(go)*ftanh(cn);
  out[BV + b*HH + h]          = hn;
  out[BV + BB*HH + b*HH + h]  = cn;
  hnew[b*HH + h] = hn;
  abf[b*KC + h]      = f2bf(hn);
  abf[b*KC + HH + h] = f2bf(ctx[b*HH + h]);
}

// K6: p_gen[b] (unchanged)
__global__ __launch_bounds__(256) void k_pgen(const float* __restrict__ genw,
    const float* __restrict__ genb, const float* __restrict__ ctx,
    const float* __restrict__ hnew, const int* __restrict__ x,
    const float* __restrict__ emb, float* __restrict__ pgen)
{
  __shared__ float red[256];
  int b = blockIdx.x, t = threadIdx.x;
  float p = 0.f;
  for (int k=t; k<KG; k+=256){
    float g = genw[k];
    float v = (k < HH) ? ctx[b*HH + k]
            : (k < 2*HH) ? hnew[b*HH + k - HH]
            : emb[(size_t)x[b]*EE + (k - 2*HH)];
    p += g*v;
  }
  red[t] = p; __syncthreads();
  for (int o=128; o; o>>=1){ if (t<o) red[t] += red[t+o]; __syncthreads(); }
  if (t==0) pgen[b] = sigm(red[0] + genb[0]);
}

// K7 v16 (final): all-asm counted-vmcnt pipeline (T3/T4). 512 blocks (2/CU),
// 4 waves = 4 M-tiles. 32KB K-half steps, double-buffered LDS; every global
// load is inline asm so no compiler vmcnt drains the pipe. Steady WAITV(9)
// leaves {next half (8) + ob (1)} in flight across raw lgkmcnt-only barriers.
// Measured R17: ~68.5us/rep at 3.0 TB/s read ~= 95% of the m13-corroborated
// pure-read streaming ceiling (~3.15 TB/s); MfmaUtil 3.7% (memory-bound).
#define PADH 2064   // padded LDS row stride (2048 + 16)
#define GLDX4(dst, ptr) asm volatile("global_load_dwordx4 %0, %1, off" : "=v"(dst) : "v"(ptr));
#define GLD1(dst, ptr)  asm volatile("global_load_dword %0, %1, off"   : "=v"(dst) : "v"(ptr));
#define WAITV(N) { asm volatile("s_waitcnt vmcnt(" #N ")" ::: "memory"); \
                   __builtin_amdgcn_sched_barrier(0); }
#define BARR() { asm volatile("s_waitcnt lgkmcnt(0)" ::: "memory"); \
                 __builtin_amdgcn_sched_barrier(0); \
                 __builtin_amdgcn_s_barrier(); \
                 __builtin_amdgcn_sched_barrier(0); }

__global__ __launch_bounds__(256, 2) void k_gemm(const float* __restrict__ out_w,
    const float* __restrict__ out_b, const unsigned short* __restrict__ abf,
    const float* __restrict__ pgen, float* __restrict__ out)
{
  __shared__ __align__(16) char wlds[2][16*PADH];   // 2 x 33 KB
  int t = threadIdx.x, w = t >> 6, lane = t & 63;
  int col = lane & 15, kg = lane >> 4;
  int bid = blockIdx.x;
  int ts = (bid * 3125) >> 9;
  int te = ((bid + 1) * 3125) >> 9;

  int gtb = ((t >> 7) << 12) + ((t & 127) << 4);   // global base in 32KB half
  int ltb = (t >> 7) * PADH + ((t & 127) << 4);    // LDS base (rows step by 2)

  // ---- prologue: every load is asm; first WAITV(9) drains pa+pgen+L(ts,0)
  bf16x8 pa0[16], pa1[16];
  const unsigned short* ap = abf + (size_t)(w*16 + col)*KC + kg*8;
  #pragma unroll
  for (int k=0; k<16; ++k){ GLDX4(pa0[k], (ap + k*32)) }
  #pragma unroll
  for (int k=0; k<16; ++k){ GLDX4(pa1[k], (ap + 512 + k*32)) }
  float pg0, pg1, pg2, pg3;
  {
    const float* pb = pgen + w*16 + kg*4;
    GLD1(pg0, (pb)) GLD1(pg1, (pb+1)) GLD1(pg2, (pb+2)) GLD1(pg3, (pb+3))
  }

  f32x4 sA_0,sA_1,sA_2,sA_3,sA_4,sA_5,sA_6,sA_7;
  f32x4 sB_0,sB_1,sB_2,sB_3,sB_4,sB_5,sB_6,sB_7;
  float obA, obB;

  #define WLOAD(S, tile_, kh_) { \
    const char* gp_ = (const char*)out_w + (size_t)(tile_)*65536 + (kh_)*2048 + gtb; \
    GLDX4(s##S##_0, (gp_)) \
    GLDX4(s##S##_1, (gp_ + 8192)) \
    GLDX4(s##S##_2, (gp_ + 16384)) \
    GLDX4(s##S##_3, (gp_ + 24576)) \
    GLDX4(s##S##_4, (gp_ + 32768)) \
    GLDX4(s##S##_5, (gp_ + 40960)) \
    GLDX4(s##S##_6, (gp_ + 49152)) \
    GLDX4(s##S##_7, (gp_ + 57344)) }

  #define WSTORE(S, buf_) { \
    char* lp_ = &wlds[buf_][0] + ltb; \
    *(f32x4*)(lp_)            = s##S##_0; \
    *(f32x4*)(lp_ + 2*PADH)   = s##S##_1; \
    *(f32x4*)(lp_ + 4*PADH)   = s##S##_2; \
    *(f32x4*)(lp_ + 6*PADH)   = s##S##_3; \
    *(f32x4*)(lp_ + 8*PADH)   = s##S##_4; \
    *(f32x4*)(lp_ + 10*PADH)  = s##S##_5; \
    *(f32x4*)(lp_ + 12*PADH)  = s##S##_6; \
    *(f32x4*)(lp_ + 14*PADH)  = s##S##_7; }

  #define COMPH(buf_, PA_) { \
    const char* rb_ = &wlds[buf_][0] + col*PADH + kg*32; \
    _Pragma("unroll") \
    for (int ks=0; ks<16; ++ks){ \
      float4 f0 = *(const float4*)(rb_ + ks*128); \
      float4 f1 = *(const float4*)(rb_ + ks*128 + 16); \
      union { bf16x8 v; unsigned int u[4]; } bb; \
      asm("v_cvt_pk_bf16_f32 %0, %1, %2" : "=v"(bb.u[0]) : "v"(f0.x), "v"(f0.y)); \
      asm("v_cvt_pk_bf16_f32 %0, %1, %2" : "=v"(bb.u[1]) : "v"(f0.z), "v"(f0.w)); \
      asm("v_cvt_pk_bf16_f32 %0, %1, %2" : "=v"(bb.u[2]) : "v"(f1.x), "v"(f1.y)); \
      asm("v_cvt_pk_bf16_f32 %0, %1, %2" : "=v"(bb.u[3]) : "v"(f1.z), "v"(f1.w)); \
      acc = __builtin_amdgcn_mfma_f32_16x16x32_bf16(PA_[ks], bb.v, acc, 0,0,0); \
    } }

  WLOAD(A, ts, 0)
  GLD1(obA, (out_b + ts*16 + col))
  WLOAD(B, ts, 1)

  f32x4 acc = {0.f,0.f,0.f,0.f};
  #pragma unroll 1
  for (int tile = ts; tile < te; ++tile){
    // ---- kh = 0
    WAITV(9)                      // L(tile,0) ready; ob(tile)+L(tile,1) stay
    WSTORE(A, 0)
    if (tile + 1 < te){
      WLOAD(A, tile+1, 0)
      GLD1(obB, (out_b + (tile+1)*16 + col))
    }
    BARR()
    COMPH(0, pa0)
    // ---- kh = 1
    if (tile + 1 < te){ WAITV(9) } else { WAITV(0) }   // L(tile,1)+ob(tile) ready
    WSTORE(B, 1)
    if (tile + 1 < te) WLOAD(B, tile+1, 1)
    BARR()
    COMPH(1, pa1)
    // ---- epilogue (wave-local)
    {
      int v = tile*16 + col;
      int b0 = w*16 + kg*4;
      out[(size_t)(b0+0)*VV + v] = pg0*(acc[0] + obA);
      out[(size_t)(b0+1)*VV + v] = pg1*(acc[1] + obA);
      out[(size_t)(b0+2)*VV + v] = pg2*(acc[2] + obA);
      out[(size_t)(b0+3)*VV + v] = pg3*(acc[3] + obA);
    }
    acc = (f32x4){0.f,0.f,0.f,0.f};
    obA = obB;
  }
  #undef WLOAD
  #undef WSTORE
  #undef COMPH
}

// K8: pointer scatter, last-duplicate-wins; weights from score+{M,L}.
__global__ __launch_bounds__(256) void k_scatter(const int* __restrict__ text,
    const float* __restrict__ score, const float* __restrict__ mlb,
    const float* __restrict__ pgen, float* __restrict__ out)
{
  __shared__ int ts[SS];
  int b = blockIdx.x, t = threadIdx.x;
  ts[t] = text[b*SS + t];
  if (t + 256 < SS) ts[t+256] = text[b*SS + t + 256];
  __syncthreads();
  float pp = 1.f - pgen[b];
  float M = mlb[b*2], invL = 1.f / mlb[b*2+1];
  #pragma unroll
  for (int rep=0; rep<2; ++rep){
    int s = t + rep*256;
    if (s < SS){
      int v = ts[s];
      bool dup = false;
      #pragma unroll 4
      for (int s2=s+1; s2<SS; ++s2) dup = dup || (ts[s2]==v);
      if (!dup){
        float wgt = __expf(score[b*SS + s] - M) * invL;
        out[(size_t)b*VV + v] += pp * wgt;
      }
    }
  }
}

extern "C" void kernel_launch(void* const* d_in, const int* in_sizes, int n_in,
                              void* d_out, int out_size, void* d_ws, size_t ws_size,
                              hipStream_t stream)
{
  const int*   x    = (const int*)  d_in[0];
  const float* enc  = (const float*)d_in[1];
  const float* h0   = (const float*)d_in[2];
  const float* c0   = (const float*)d_in[3];
  const int*   text = (const int*)  d_in[4];
  const float* emb  = (const float*)d_in[6];
  const float* Vw   = (const float*)d_in[7];
  const float* Vb   = (const float*)d_in[8];
  const float* genw = (const float*)d_in[9];
  const float* genb = (const float*)d_in[10];
  const float* outw = (const float*)d_in[11];
  const float* outb = (const float*)d_in[12];
  const float* Wih  = (const float*)d_in[13];
  const float* Whh  = (const float*)d_in[14];
  const float* bih  = (const float*)d_in[15];
  const float* bhh  = (const float*)d_in[16];
  float* out = (float*)d_out;

  float* ws     = (float*)d_ws;
  float* score  = ws + WS_SCORE;
  float* ml     = ws + WS_ML;
  float* mlb    = ws + WS_MLB;
  float* ctx    = ws + WS_CTX;
  float* hnew   = ws + WS_HNEW;
  float* g0     = ws + WS_G0;
  float* g1     = ws + WS_G1;
  float* g2     = ws + WS_G2;
  float* g3     = ws + WS_G3;
  float* pgen   = ws + WS_PGEN;
  float* part   = ws + WS_PART;
  unsigned short* abf = (unsigned short*)(ws + WS_ABF);
  unsigned short* ad1 = (unsigned short*)(ws + WS_AD1);
  unsigned short* ad2 = (unsigned short*)(ws + WS_AD2);

  k_scorectx<<<848, 256, 0, stream>>>(x, emb, enc, h0, Vw, Vb, score, part, ml, ad1, ad2);
  k_ctx_reduce<<<64, 256, 0, stream>>>(part, ml, ctx, ad1, mlb);
  k_gates<<<256, 128, 0, stream>>>(Wih, Whh, ad1, ad2, g0, g1, g2, g3);
  k_lstm<<<128, 256, 0, stream>>>(c0, bih, bhh, g0, g1, g2, g3, ctx, hnew, abf, out);
  k_pgen<<<64, 256, 0, stream>>>(genw, genb, ctx, hnew, x, emb, pgen);
  k_gemm<<<512, 256, 0, stream>>>(outw, outb, abf, pgen, out);
  k_scatter<<<64, 256, 0, stream>>>(text, score, mlb, pgen, out);
}